// Round 12
// baseline (172.385 us; speedup 1.0000x reference)
//
#include <hip/hip_runtime.h>

typedef short short8 __attribute__((ext_vector_type(8)));
typedef float f32x4 __attribute__((ext_vector_type(4)));
typedef unsigned int u32x2 __attribute__((ext_vector_type(2)));
typedef unsigned int u32x4 __attribute__((ext_vector_type(4)));

#define N_NODES   100000
#define E_KEEP    1000000
#define E_TOTAL_N 1100000
#define EDGE_OUT_BASE 12800000L

#define STG_STRIDE 272   // 32 rows x 128 bf16, padded (17 quads, odd)

__device__ __forceinline__ unsigned short f2bf(float f) {
  unsigned int u = __builtin_bit_cast(unsigned int, f);
  u += 0x7fffu + ((u >> 16) & 1u);
  return (unsigned short)(u >> 16);
}

// v_cvt_pk_bf16_f32 (acquitted in R11): lo->bits[15:0], hi->bits[31:16], RNE
__device__ __forceinline__ unsigned int cvtpk(float lo, float hi) {
  unsigned int r;
  asm("v_cvt_pk_bf16_f32 %0, %1, %2" : "=v"(r) : "v"(lo), "v"(hi));
  return r;
}
__device__ __forceinline__ unsigned int pack2relu(float lo, float hi) {
  return cvtpk(fmaxf(lo, 0.f), fmaxf(hi, 0.f));
}

// nw2/ew2 fp32 [128][128] -> bf16 W2^T in ws (node [0:16384], edge [16384:32768])
__global__ void transpose_w2(const float* __restrict__ nw2,
                             const float* __restrict__ ew2,
                             unsigned short* __restrict__ ws) {
  int idx = blockIdx.x * 256 + threadIdx.x;
  for (int i = idx; i < 32768; i += 8192) {
    int m = i >> 14;
    int w = i & 16383;
    int k = w >> 7;
    int n = w & 127;
    const float* src = m ? ew2 : nw2;
    ws[m * 16384 + n * 128 + k] = f2bf(src[w]);  // W2T[n][k] = W2[k][n]
  }
}

struct SmemLayout {
  float w1f[7 * 128];           // layer-1 weights (edges use first 3 rows)
  float b1f[128];
  float b2f[128];
  float attr[256 * 7];          // per-row attrs, stride NA (3 or 7, coprime w/ 32)
  char  stg[2][32 * STG_STRIDE];  // double-buffered bf16 output stage
};

// Block: 256 thr = 4 waves (rg = wid&1 rows, wc = wid>>1 cols-of-64).
// Phase A: gather attrs once per row -> LDS.
// Per iter (ONE barrier):
//   BC: lane computes its h1 B-fragment IN REGISTERS (R2-proven layout:
//       lane (g,c) owns h1[row=c][kk*32+g*8..+8]), 16 MFMA, pack acc+b2 -> stg[s&1]
//   bar
//   C': linear stage read -> full-line coalesced f32 stores
template<bool IS_EDGE>
__device__ __forceinline__ void run_path(
    const float* __restrict__ src,   // pos (edges) or x (nodes)
    const int* __restrict__ ei,
    const float* __restrict__ w1,
    const float* __restrict__ b1,
    const float* __restrict__ b2,
    const unsigned short* __restrict__ w2t,
    float* __restrict__ outp, long out_base, int row_limit,
    int bid, SmemLayout& sm)
{
  constexpr int NA = IS_EDGE ? 3 : 7;
  const int t = threadIdx.x;

  if (t < 128) { sm.b1f[t] = b1[t]; sm.b2f[t] = b2[t]; }
  for (int i = t; i < NA * 128; i += 256) sm.w1f[i] = w1[i];

  // ---- phase A: attrs for this block's 256 rows (1 row per thread) ----
  {
    int r  = bid * 256 + t;
    int rl = r < row_limit ? r : row_limit - 1;
    if (IS_EDGE) {
      int si = ei[rl];
      int di = ei[E_TOTAL_N + rl];
      float ax = src[si * 3]     - src[di * 3];
      float ay = src[si * 3 + 1] - src[di * 3 + 1];
      sm.attr[t * 3 + 0] = ax;
      sm.attr[t * 3 + 1] = ay;
      sm.attr[t * 3 + 2] = sqrtf(ax * ax + ay * ay);
    } else {
#pragma unroll
      for (int cc = 0; cc < 7; ++cc) sm.attr[t * 7 + cc] = src[rl * 7 + cc];
    }
  }

  const int lane = t & 63;
  const int wid  = t >> 6;
  const int rg   = wid & 1;
  const int wc   = wid >> 1;
  const int c    = lane & 15;
  const int g    = lane >> 4;

  // W2^T MFMA A-fragments (R2-proven): lane holds n = wc*64+nf*16+c, k = kk*32+g*8..+8
  short8 wfrag[4][4];
#pragma unroll
  for (int nf = 0; nf < 4; ++nf)
#pragma unroll
    for (int kk = 0; kk < 4; ++kk)
      wfrag[nf][kk] = *(const short8*)(w2t + (wc * 64 + nf * 16 + c) * 128 + kk * 32 + g * 8);

  const int rrow = rg * 16 + c;     // tile-local row this lane computes/consumes

  __syncthreads();   // attrs + weights visible

  f32x4 b2v[4];
#pragma unroll
  for (int nf = 0; nf < 4; ++nf)
    b2v[nf] = *(const f32x4*)&sm.b2f[wc * 64 + nf * 16 + g * 4];

  for (int s = 0; s < 8; ++s) {
    // ---- BC: h1 fragment in regs + MFMA + pack to stage ----
    {
      float a[NA];
#pragma unroll
      for (int cc = 0; cc < NA; ++cc)
        a[cc] = sm.attr[(s * 32 + rrow) * NA + cc];

      f32x4 acc0 = {}, acc1 = {}, acc2 = {}, acc3 = {};
#pragma unroll
      for (int kk = 0; kk < 4; ++kk) {
        int k0g = kk * 32 + g * 8;
        f32x4 h0 = *(const f32x4*)&sm.b1f[k0g];
        f32x4 h1v = *(const f32x4*)&sm.b1f[k0g + 4];
#pragma unroll
        for (int cc = 0; cc < NA; ++cc) {
          h0  += a[cc] * *(const f32x4*)&sm.w1f[cc * 128 + k0g];
          h1v += a[cc] * *(const f32x4*)&sm.w1f[cc * 128 + k0g + 4];
        }
        u32x4 hv;
        hv[0] = pack2relu(h0[0], h0[1]);
        hv[1] = pack2relu(h0[2], h0[3]);
        hv[2] = pack2relu(h1v[0], h1v[1]);
        hv[3] = pack2relu(h1v[2], h1v[3]);
        short8 hf = __builtin_bit_cast(short8, hv);
        acc0 = __builtin_amdgcn_mfma_f32_16x16x32_bf16(wfrag[0][kk], hf, acc0, 0, 0, 0);
        acc1 = __builtin_amdgcn_mfma_f32_16x16x32_bf16(wfrag[1][kk], hf, acc1, 0, 0, 0);
        acc2 = __builtin_amdgcn_mfma_f32_16x16x32_bf16(wfrag[2][kk], hf, acc2, 0, 0, 0);
        acc3 = __builtin_amdgcn_mfma_f32_16x16x32_bf16(wfrag[3][kk], hf, acc3, 0, 0, 0);
      }

      char* wp = sm.stg[s & 1] + rrow * STG_STRIDE + (wc * 64 + g * 4) * 2;
      f32x4 av[4] = {acc0 + b2v[0], acc1 + b2v[1], acc2 + b2v[2], acc3 + b2v[3]};
#pragma unroll
      for (int nf = 0; nf < 4; ++nf) {
        u32x2 d;
        d[0] = cvtpk(av[nf][0], av[nf][1]);
        d[1] = cvtpk(av[nf][2], av[nf][3]);
        *(u32x2*)(wp + nf * 32) = d;
      }
    }

    __syncthreads();   // stage[s&1] ready (WAR across iters ordered by next bar)

    // ---- C': linear stage read -> full-line coalesced f32 stores ----
    {
      const char* stg = sm.stg[s & 1];
      int r0 = bid * 256 + s * 32;
#pragma unroll
      for (int p = 0; p < 2; ++p) {
        int u   = p * 256 + t;          // 16B unit within 32x(128bf16) tile
        int row = u >> 4;
        int k16 = u & 15;
        if (r0 + row < row_limit) {
          short8 v = *(const short8*)(stg + row * STG_STRIDE + k16 * 16);
          f32x4 lo, hi;
#pragma unroll
          for (int j = 0; j < 4; ++j) {
            lo[j] = __builtin_bit_cast(float, ((unsigned int)(unsigned short)v[j]) << 16);
            hi[j] = __builtin_bit_cast(float, ((unsigned int)(unsigned short)v[4 + j]) << 16);
          }
          float* op = outp + out_base + (long)(r0 + row) * 128 + k16 * 8;
          *(f32x4*)op       = lo;
          *(f32x4*)(op + 4) = hi;
        }
      }
    }
  }
}

__global__ __launch_bounds__(256, 4) void encoder_kernel(
    const float* __restrict__ x,
    const float* __restrict__ pos,
    const int* __restrict__ ei,
    const float* __restrict__ nw1,
    const float* __restrict__ nb1,
    const float* __restrict__ nb2,
    const float* __restrict__ ew1,
    const float* __restrict__ eb1,
    const float* __restrict__ eb2,
    const unsigned short* __restrict__ ws,
    float* __restrict__ outp,
    int nodeBlocks)
{
  __shared__ SmemLayout sm;
  int bid = blockIdx.x;
  if (bid < nodeBlocks) {
    run_path<false>(x, nullptr, nw1, nb1, nb2, ws, outp, 0L, N_NODES, bid, sm);
  } else {
    run_path<true>(pos, ei, ew1, eb1, eb2, ws + 16384, outp, EDGE_OUT_BASE,
                   E_KEEP, bid - nodeBlocks, sm);
  }
}

extern "C" void kernel_launch(void* const* d_in, const int* in_sizes, int n_in,
                              void* d_out, int out_size, void* d_ws, size_t ws_size,
                              hipStream_t stream) {
  const float* x   = (const float*)d_in[0];
  const float* pos = (const float*)d_in[1];
  const int*   ei  = (const int*)d_in[2];
  const float* nw1 = (const float*)d_in[3];
  const float* nb1 = (const float*)d_in[4];
  const float* nw2 = (const float*)d_in[5];
  const float* nb2 = (const float*)d_in[6];
  const float* ew1 = (const float*)d_in[7];
  const float* eb1 = (const float*)d_in[8];
  const float* ew2 = (const float*)d_in[9];
  const float* eb2 = (const float*)d_in[10];
  unsigned short* ws   = (unsigned short*)d_ws;
  float*          outp = (float*)d_out;

  transpose_w2<<<32, 256, 0, stream>>>(nw2, ew2, ws);

  int nodeBlocks = (N_NODES + 255) / 256;  // 391
  int edgeBlocks = (E_KEEP + 255) / 256;   // 3907
  encoder_kernel<<<nodeBlocks + edgeBlocks, 256, 0, stream>>>(
      x, pos, ei, nw1, nb1, nb2, ew1, eb1, eb2, ws, outp, nodeBlocks);
}

// Round 13
// 169.750 us; speedup vs baseline: 1.0155x; 1.0155x over previous
//
#include <hip/hip_runtime.h>

typedef short short8 __attribute__((ext_vector_type(8)));
typedef float f32x4 __attribute__((ext_vector_type(4)));
typedef unsigned int u32x2 __attribute__((ext_vector_type(2)));
typedef unsigned int u32x4 __attribute__((ext_vector_type(4)));

#define N_NODES   100000
#define E_KEEP    1000000
#define E_TOTAL_N 1100000
#define EDGE_OUT_BASE 12800000L

// wave-private stage tile: 16 rows x 64 bf16, row stride 128 -> 144 bytes
// (9 quads, odd => diagonal bank-quad mapping, conflict-free)
#define WSTG_STRIDE 144

__device__ __forceinline__ unsigned short f2bf(float f) {
  unsigned int u = __builtin_bit_cast(unsigned int, f);
  u += 0x7fffu + ((u >> 16) & 1u);
  return (unsigned short)(u >> 16);
}

// v_cvt_pk_bf16_f32 (acquitted R11): lo->bits[15:0], hi->bits[31:16], RNE
__device__ __forceinline__ unsigned int cvtpk(float lo, float hi) {
  unsigned int r;
  asm("v_cvt_pk_bf16_f32 %0, %1, %2" : "=v"(r) : "v"(lo), "v"(hi));
  return r;
}
__device__ __forceinline__ unsigned int pack2relu(float lo, float hi) {
  return cvtpk(fmaxf(lo, 0.f), fmaxf(hi, 0.f));
}

// nw2/ew2 fp32 [128][128] -> bf16 W2^T in ws (node [0:16384], edge [16384:32768])
__global__ void transpose_w2(const float* __restrict__ nw2,
                             const float* __restrict__ ew2,
                             unsigned short* __restrict__ ws) {
  int idx = blockIdx.x * 256 + threadIdx.x;
  for (int i = idx; i < 32768; i += 8192) {
    int m = i >> 14;
    int w = i & 16383;
    int k = w >> 7;
    int n = w & 127;
    const float* src = m ? ew2 : nw2;
    ws[m * 16384 + n * 128 + k] = f2bf(src[w]);  // W2T[n][k] = W2[k][n]
  }
}

struct SmemLayout {
  float w1f[7 * 128];            // layer-1 weights (edges use first 3 rows)
  float b1f[128];
  float b2f[128];
  float attr[256 * 7];           // per-row attrs, stride NA (3 or 7)
  char  wstg[4][16 * WSTG_STRIDE];  // WAVE-PRIVATE bf16 output stage tiles
};

// Block: 256 thr = 4 waves (rg = wid&1 rows-of-16, wc = wid>>1 cols-of-64).
// ONE barrier total (after attr staging). Steady loop is barrier-free:
//   - h1 B-fragment computed in registers (R2/R12-proven layout)
//   - 16 MFMA
//   - acc+b2 packed bf16 into the wave's PRIVATE stage tile (wave-internal
//     LDS ordering only -> no __syncthreads)
//   - linear re-read -> 128B-aligned full-line f32 stores; stores are never
//     drained in-loop (no vmcnt(0)+s_barrier), so the store stream stays deep.
template<bool IS_EDGE>
__device__ __forceinline__ void run_path(
    const float* __restrict__ src,   // pos (edges) or x (nodes)
    const int* __restrict__ ei,
    const float* __restrict__ w1,
    const float* __restrict__ b1,
    const float* __restrict__ b2,
    const unsigned short* __restrict__ w2t,
    float* __restrict__ outp, long out_base, int row_limit,
    int bid, SmemLayout& sm)
{
  constexpr int NA = IS_EDGE ? 3 : 7;
  const int t = threadIdx.x;

  if (t < 128) { sm.b1f[t] = b1[t]; sm.b2f[t] = b2[t]; }
  for (int i = t; i < NA * 128; i += 256) sm.w1f[i] = w1[i];

  // ---- phase A: attrs for this block's 256 rows (1 row per thread) ----
  {
    int r  = bid * 256 + t;
    int rl = r < row_limit ? r : row_limit - 1;
    if (IS_EDGE) {
      int si = ei[rl];
      int di = ei[E_TOTAL_N + rl];
      float ax = src[si * 3]     - src[di * 3];
      float ay = src[si * 3 + 1] - src[di * 3 + 1];
      sm.attr[t * 3 + 0] = ax;
      sm.attr[t * 3 + 1] = ay;
      sm.attr[t * 3 + 2] = sqrtf(ax * ax + ay * ay);
    } else {
#pragma unroll
      for (int cc = 0; cc < 7; ++cc) sm.attr[t * 7 + cc] = src[rl * 7 + cc];
    }
  }

  const int lane = t & 63;
  const int wid  = t >> 6;
  const int rg   = wid & 1;
  const int wc   = wid >> 1;
  const int c    = lane & 15;
  const int g    = lane >> 4;

  // W2^T MFMA A-fragments (R2-proven): lane holds n = wc*64+nf*16+c, k = kk*32+g*8..+8
  short8 wfrag[4][4];
#pragma unroll
  for (int nf = 0; nf < 4; ++nf)
#pragma unroll
    for (int kk = 0; kk < 4; ++kk)
      wfrag[nf][kk] = *(const short8*)(w2t + (wc * 64 + nf * 16 + c) * 128 + kk * 32 + g * 8);

  __syncthreads();   // the ONLY block-wide barrier: attrs + weights visible

  f32x4 b2v[4];
#pragma unroll
  for (int nf = 0; nf < 4; ++nf)
    b2v[nf] = *(const f32x4*)&sm.b2f[wc * 64 + nf * 16 + g * 4];

  char* mystg = sm.wstg[wid];
  const int srow  = lane >> 3;      // store-phase row-within-8
  const int sunit = lane & 7;       // store-phase 16B unit (8 bf16 cols)

  for (int s = 0; s < 8; ++s) {
    const int rrow = rg * 16 + c;   // tile-local row this lane computes

    // ---- compute: h1 fragment in regs + 16 MFMA ----
    float a[NA];
#pragma unroll
    for (int cc = 0; cc < NA; ++cc)
      a[cc] = sm.attr[(s * 32 + rrow) * NA + cc];

    f32x4 acc0 = {}, acc1 = {}, acc2 = {}, acc3 = {};
#pragma unroll
    for (int kk = 0; kk < 4; ++kk) {
      int k0g = kk * 32 + g * 8;
      f32x4 h0 = *(const f32x4*)&sm.b1f[k0g];
      f32x4 h1v = *(const f32x4*)&sm.b1f[k0g + 4];
#pragma unroll
      for (int cc = 0; cc < NA; ++cc) {
        h0  += a[cc] * *(const f32x4*)&sm.w1f[cc * 128 + k0g];
        h1v += a[cc] * *(const f32x4*)&sm.w1f[cc * 128 + k0g + 4];
      }
      u32x4 hv;
      hv[0] = pack2relu(h0[0], h0[1]);
      hv[1] = pack2relu(h0[2], h0[3]);
      hv[2] = pack2relu(h1v[0], h1v[1]);
      hv[3] = pack2relu(h1v[2], h1v[3]);
      short8 hf = __builtin_bit_cast(short8, hv);
      acc0 = __builtin_amdgcn_mfma_f32_16x16x32_bf16(wfrag[0][kk], hf, acc0, 0, 0, 0);
      acc1 = __builtin_amdgcn_mfma_f32_16x16x32_bf16(wfrag[1][kk], hf, acc1, 0, 0, 0);
      acc2 = __builtin_amdgcn_mfma_f32_16x16x32_bf16(wfrag[2][kk], hf, acc2, 0, 0, 0);
      acc3 = __builtin_amdgcn_mfma_f32_16x16x32_bf16(wfrag[3][kk], hf, acc3, 0, 0, 0);
    }

    // ---- pack acc+b2 -> WAVE-PRIVATE stage (no cross-wave sync needed) ----
    {
      f32x4 av[4] = {acc0 + b2v[0], acc1 + b2v[1], acc2 + b2v[2], acc3 + b2v[3]};
      char* wp = mystg + c * WSTG_STRIDE + g * 8;
#pragma unroll
      for (int nf = 0; nf < 4; ++nf) {
        u32x2 d;
        d[0] = cvtpk(av[nf][0], av[nf][1]);
        d[1] = cvtpk(av[nf][2], av[nf][3]);
        *(u32x2*)(wp + nf * 32) = d;   // col byte off = (nf*16+g*4)*2
      }
    }

    // ---- store: linear read of private tile -> full-line f32 stores ----
    // (compiler inserts lgkmcnt for the read-after-write; same-wave LDS is
    //  in-order, so no barrier. Global stores are fire-and-forget.)
    {
      int r0w = bid * 256 + s * 32 + rg * 16;
#pragma unroll
      for (int p = 0; p < 2; ++p) {
        int row = p * 8 + srow;
        short8 v = *(const short8*)(mystg + row * WSTG_STRIDE + sunit * 16);
        f32x4 lo, hi;
#pragma unroll
        for (int j = 0; j < 4; ++j) {
          lo[j] = __builtin_bit_cast(float, ((unsigned int)(unsigned short)v[j]) << 16);
          hi[j] = __builtin_bit_cast(float, ((unsigned int)(unsigned short)v[4 + j]) << 16);
        }
        if (r0w + row < row_limit) {
          float* op = outp + out_base + (long)(r0w + row) * 128 + wc * 64 + sunit * 8;
          *(f32x4*)op       = lo;
          *(f32x4*)(op + 4) = hi;
        }
      }
    }
  }
}

__global__ __launch_bounds__(256, 4) void encoder_kernel(
    const float* __restrict__ x,
    const float* __restrict__ pos,
    const int* __restrict__ ei,
    const float* __restrict__ nw1,
    const float* __restrict__ nb1,
    const float* __restrict__ nb2,
    const float* __restrict__ ew1,
    const float* __restrict__ eb1,
    const float* __restrict__ eb2,
    const unsigned short* __restrict__ ws,
    float* __restrict__ outp,
    int nodeBlocks)
{
  __shared__ SmemLayout sm;
  int bid = blockIdx.x;
  if (bid < nodeBlocks) {
    run_path<false>(x, nullptr, nw1, nb1, nb2, ws, outp, 0L, N_NODES, bid, sm);
  } else {
    run_path<true>(pos, ei, ew1, eb1, eb2, ws + 16384, outp, EDGE_OUT_BASE,
                   E_KEEP, bid - nodeBlocks, sm);
  }
}

extern "C" void kernel_launch(void* const* d_in, const int* in_sizes, int n_in,
                              void* d_out, int out_size, void* d_ws, size_t ws_size,
                              hipStream_t stream) {
  const float* x   = (const float*)d_in[0];
  const float* pos = (const float*)d_in[1];
  const int*   ei  = (const int*)d_in[2];
  const float* nw1 = (const float*)d_in[3];
  const float* nb1 = (const float*)d_in[4];
  const float* nw2 = (const float*)d_in[5];
  const float* nb2 = (const float*)d_in[6];
  const float* ew1 = (const float*)d_in[7];
  const float* eb1 = (const float*)d_in[8];
  const float* ew2 = (const float*)d_in[9];
  const float* eb2 = (const float*)d_in[10];
  unsigned short* ws   = (unsigned short*)d_ws;
  float*          outp = (float*)d_out;

  transpose_w2<<<32, 256, 0, stream>>>(nw2, ew2, ws);

  int nodeBlocks = (N_NODES + 255) / 256;  // 391
  int edgeBlocks = (E_KEEP + 255) / 256;   // 3907
  encoder_kernel<<<nodeBlocks + edgeBlocks, 256, 0, stream>>>(
      x, pos, ei, nw1, nb1, nb2, ew1, eb1, eb2, ws, outp, nodeBlocks);
}